// Round 18
// baseline (156.774 us; speedup 1.0000x reference)
//
#include <hip/hip_runtime.h>
#include <hip/hip_bf16.h>

// B=2, D=1024, N=2048, H=16, DH=64
#define BATCH 2
#define DMODEL 1024
#define SEQ 2048
#define NHEAD 16
#define DHEAD 64
#define BH (BATCH*NHEAD)   // 32
#define COLS (BATCH*SEQ)   // 4096

typedef __attribute__((ext_vector_type(8))) short bf16x8;
typedef __attribute__((ext_vector_type(4))) float f32x4;
typedef __attribute__((ext_vector_type(16))) float f32x16;

__device__ inline unsigned short f2bf(float f) {
    unsigned u = __builtin_bit_cast(unsigned, f);
    unsigned r = (u + 0x7FFFu + ((u >> 16) & 1u)) >> 16;
    return (unsigned short)r;
}

__device__ inline f32x4 mfma16(bf16x8 a, bf16x8 b, f32x4 c) {
    return __builtin_amdgcn_mfma_f32_16x16x32_bf16(a, b, c, 0, 0, 0);
}
__device__ inline f32x16 mfma32(bf16x8 a, bf16x8 b, f32x16 c) {
    return __builtin_amdgcn_mfma_f32_32x32x16_bf16(a, b, c, 0, 0, 0);
}

__device__ __forceinline__ void gload_lds16(const unsigned short* g, unsigned short* l) {
    __builtin_amdgcn_global_load_lds(
        (const __attribute__((address_space(1))) unsigned int*)g,
        (__attribute__((address_space(3))) unsigned int*)l, 16, 0, 0);
}

__device__ inline unsigned cvtpk(float lo, float hi) {
    unsigned r;
    asm("v_cvt_pk_bf16_f32 %0, %1, %2" : "=v"(r) : "v"(lo), "v"(hi));
    return r;
}
__device__ inline float fexp2(float x) {
    float r;
    asm("v_exp_f32 %0, %1" : "=v"(r) : "v"(x));
    return r;
}

// ---------------- convert 4 weight matrices fp32 -> bf16 ----------------
__global__ __launch_bounds__(256) void cvt_w(
    const float* __restrict__ w0, const float* __restrict__ w1,
    const float* __restrict__ w2, const float* __restrict__ w3,
    unsigned short* __restrict__ out)
{
    int which = blockIdx.y;
    const float* src = (which == 0) ? w0 : (which == 1) ? w1 : (which == 2) ? w2 : w3;
    size_t base = (size_t)which * (DMODEL * DMODEL);
    size_t i = ((size_t)blockIdx.x * 256 + threadIdx.x) * 4;
    float4 v = *(const float4*)&src[i];
    ushort4 o;
    o.x = f2bf(v.x); o.y = f2bf(v.y); o.z = f2bf(v.z); o.w = f2bf(v.w);
    *(ushort4*)&out[base + i] = o;
}

// ---------------- mask -> ballot words + permuted bf16 indicator rows ----------------
__global__ __launch_bounds__(64) void prep_mask(
    const int* __restrict__ mask, unsigned long long* __restrict__ mw,
    unsigned short* __restrict__ maskvb)
{
    int lane = threadIdx.x;
    int tile = blockIdx.x;            // [0,64): mb = tile>>5, tt = tile&31
    int mb = tile >> 5, tt = tile & 31;
    int mv = mask[mb * SEQ + tt * 64 + lane];
    unsigned long long bits = __ballot(mv != 0);
    if (lane == 0) mw[tile] = bits;
    // quartet-permuted indicator (same permute as V storage)
    int q2 = (lane >> 2) & 3;
    int q2s = ((q2 & 1) << 1) | (q2 >> 1);   // 0->0, 1->2, 2->1, 3->3
    int pp = (lane & ~15) | (q2s << 2) | (lane & 3);
    maskvb[mb * SEQ + tt * 64 + pp] = mv ? 0x3F80 : 0;   // bf16 1.0 / 0.0
}

// ---------------- transpose query [B][D][N] fp32 -> Xt [B][N][D] bf16 ----------------
__global__ __launch_bounds__(256) void transpose_q(
    const float* __restrict__ q, unsigned short* __restrict__ Xt)
{
    __shared__ float tile[32][33];
    int b = blockIdx.z;
    int d0 = blockIdx.y * 32, n0 = blockIdx.x * 32;
    int tx = threadIdx.x, ty = threadIdx.y;  // 32 x 8
#pragma unroll
    for (int i = 0; i < 32; i += 8)
        tile[ty + i][tx] = q[(size_t)b * DMODEL * SEQ + (size_t)(d0 + ty + i) * SEQ + n0 + tx];
    __syncthreads();
#pragma unroll
    for (int i = 0; i < 32; i += 8)
        Xt[(size_t)b * SEQ * DMODEL + (size_t)(n0 + ty + i) * DMODEL + d0 + tx] = f2bf(tile[tx][ty + i]);
}

// ---------------- fused QKV GEMM, m97 128x128 structure ----------------
// K stored PRE-FRAGMENTED: Kg[bh][tile 32][frag 8 = c*2+hi][k 64][8 bf16]
//   (pure (c,hi) d-axis blocking; no permute -- QK^T inner dim is d).
// V stored PRE-FRAGMENTED: Vg[bh][tile 32][frag 8 = ks*2+hi][d 64][8 bf16],
//   quartet-permuted within each 16-key group and ZEROED at masked keys.
__global__ __launch_bounds__(256) void gemm_qkv(
    const unsigned short* __restrict__ Xt,   // [4096][1024]
    const unsigned short* __restrict__ W3,   // [3072][1024]
    const float* __restrict__ bq, const float* __restrict__ bk, const float* __restrict__ bv,
    const int* __restrict__ mask,
    unsigned short* __restrict__ Qb, unsigned short* __restrict__ Kbuf,
    unsigned short* __restrict__ Vtb)
{
    const int K = DMODEL;
    __shared__ unsigned short sA[128 * 32];
    __shared__ unsigned short sB[128 * 32];
    int t = threadIdx.x, lane = t & 63, w = t >> 6;
    int wr = w >> 1, wc = w & 1;
    int tt0 = blockIdx.y * 128;        // token tile
    int ct0 = blockIdx.x * 128;        // e tile within stacked 3072
    int mat = ct0 >> 10, ec0 = ct0 & 1023;
    const float* bs = (mat == 0) ? bq : (mat == 1) ? bk : bv;
    int rl = lane & 15, ko = (lane >> 4) << 3;
    int srow = lane >> 2, scol = (lane & 3) << 3;

    f32x4 acc[4][4] = {};
    for (int kb = 0; kb < K; kb += 32) {
        __syncthreads();
        gload_lds16(&Xt[(size_t)(tt0 + w * 32 + srow) * K + kb + scol],      &sA[(w * 32) * 32]);
        gload_lds16(&Xt[(size_t)(tt0 + w * 32 + 16 + srow) * K + kb + scol], &sA[(w * 32 + 16) * 32]);
        gload_lds16(&W3[(size_t)(ct0 + w * 32 + srow) * K + kb + scol],      &sB[(w * 32) * 32]);
        gload_lds16(&W3[(size_t)(ct0 + w * 32 + 16 + srow) * K + kb + scol], &sB[(w * 32 + 16) * 32]);
        __syncthreads();
        bf16x8 af[4], bfr[4];
#pragma unroll
        for (int m = 0; m < 4; m++)
            af[m] = *(const bf16x8*)&sA[(wr * 64 + m * 16 + rl) * 32 + ko];
#pragma unroll
        for (int n = 0; n < 4; n++)
            bfr[n] = *(const bf16x8*)&sB[(wc * 64 + n * 16 + rl) * 32 + ko];
#pragma unroll
        for (int m = 0; m < 4; m++)
#pragma unroll
            for (int n = 0; n < 4; n++)
                acc[m][n] = mfma16(af[m], bfr[n], acc[m][n]);
    }

    const float QS = 0.125f;   // exact power of two
    int rowb = (lane >> 4) * 4, col = lane & 15;
#pragma unroll
    for (int m = 0; m < 4; m++) {
#pragma unroll
        for (int n = 0; n < 4; n++) {
            int ee = ec0 + wc * 64 + n * 16 + col;
            int hh = ee >> 6, dd = ee & 63;
            float bias = bs[ee];
#pragma unroll
            for (int r = 0; r < 4; r++) {
                int tk = tt0 + wr * 64 + m * 16 + rowb + r;
                int b = tk >> 11, nn = tk & (SEQ - 1);
                float v = acc[m][n][r] + bias;
                if (mat == 0) {
                    v *= QS;
                    Qb[((size_t)(b * NHEAD + hh) * SEQ + nn) * DHEAD + dd] = f2bf(v);
                } else if (mat == 1) {
                    // fragment layout: [bh][tile][frag=dd>>3][k=nn&63][jj=dd&7]
                    int tl = nn >> 6, kk = nn & 63;
                    Kbuf[((((size_t)(b * NHEAD + hh) * 32 + tl) * 8 + (dd >> 3)) * 64 + kk) * 8 + (dd & 7)] = f2bf(v);
                } else {
                    // zero masked keys; quartet permute; store into fragment layout
                    if (mask[(hh & 1) * SEQ + nn] == 0) v = 0.f;
                    int q2 = (nn >> 2) & 3;
                    int q2s = ((q2 & 1) << 1) | (q2 >> 1);   // 0->0, 1->2, 2->1, 3->3
                    int np = (nn & ~15) | (q2s << 2) | (nn & 3);
                    int tl = np >> 6, kk = np & 63;
                    int ks = kk >> 4, hi2 = (kk >> 3) & 1, jj = kk & 7;
                    Vtb[((((size_t)(b * NHEAD + hh) * 32 + tl) * 8 + ks * 2 + hi2) * 64 + dd) * 8 + jj] = f2bf(v);
                }
            }
        }
    }
}

// ---------------- output GEMM: out[e,c] = sum_d Wo[e,d]*Zt[c,d] + bo[e] ----------------
__global__ __launch_bounds__(256) void gemm_out(
    const unsigned short* __restrict__ A,    // Wo bf16 [1024][1024]
    const unsigned short* __restrict__ Bt,   // Zt [4096][1024]
    const float* __restrict__ bias,
    float* __restrict__ outf)
{
    const int K = DMODEL;
    __shared__ unsigned short sA[128 * 32];
    __shared__ unsigned short sB[64 * 32];
    int t = threadIdx.x, lane = t & 63, w = t >> 6;
    int wr = w >> 1, wc = w & 1;
    int et0 = blockIdx.y * 128, ct0 = blockIdx.x * 64;
    int rl = lane & 15, ko = (lane >> 4) << 3;
    int srow = lane >> 2, scol = (lane & 3) << 3;

    f32x4 acc[4][2] = {};
    for (int kb = 0; kb < K; kb += 32) {
        __syncthreads();
        gload_lds16(&A[(size_t)(et0 + w * 16 + srow) * K + kb + scol],      &sA[(w * 16) * 32]);
        gload_lds16(&A[(size_t)(et0 + 64 + w * 16 + srow) * K + kb + scol], &sA[(64 + w * 16) * 32]);
        gload_lds16(&Bt[(size_t)(ct0 + w * 16 + srow) * K + kb + scol],     &sB[(w * 16) * 32]);
        __syncthreads();
        bf16x8 af[4], bfr[2];
#pragma unroll
        for (int m = 0; m < 4; m++)
            af[m] = *(const bf16x8*)&sA[(wr * 64 + m * 16 + rl) * 32 + ko];
#pragma unroll
        for (int n = 0; n < 2; n++)
            bfr[n] = *(const bf16x8*)&sB[(wc * 32 + n * 16 + rl) * 32 + ko];
#pragma unroll
        for (int m = 0; m < 4; m++)
#pragma unroll
            for (int n = 0; n < 2; n++)
                acc[m][n] = mfma16(af[m], bfr[n], acc[m][n]);
    }

    int rowb = (lane >> 4) * 4, col = lane & 15;
#pragma unroll
    for (int m = 0; m < 4; m++) {
#pragma unroll
        for (int n = 0; n < 2; n++) {
            int c = ct0 + wc * 32 + n * 16 + col;
            int b = c >> 11, nn = c & (SEQ - 1);
#pragma unroll
            for (int r = 0; r < 4; r++) {
                int e = et0 + wr * 64 + m * 16 + rowb + r;
                outf[((size_t)b * DMODEL + e) * SEQ + nn] = acc[m][n][r] + bias[e];
            }
        }
    }
}

// ---------------- attention: barrier-free, all operands coalesced from global ----------------
// K and V both pre-fragmented in memory: per tile, 8 K-loads + 8 V-loads +
// 4 mask-loads (all dwordx4, L2-resident), 20 MFMA, in-register softmax.
// No LDS, no __syncthreads: waves independent, compiler free to pipeline.
__global__ __launch_bounds__(256) void attn(
    const unsigned short* __restrict__ Q,
    const unsigned short* __restrict__ Kg,
    const unsigned short* __restrict__ Vt,
    const unsigned long long* __restrict__ mwords,
    const unsigned short* __restrict__ maskvb,
    unsigned short* __restrict__ Zt)
{
    int bid = blockIdx.x;                 // 512 blocks; bid%8 -> XCD
    int xcd = bid & 7, slot = bid >> 3;
    int bh = xcd + 8 * (slot >> 4);       // 4 heads per XCD
    int qb = slot & 15;
    int b = bh >> 4, h = bh & 15;
    int mb = bh & (BATCH - 1);            // tile semantics: head bh uses mask row bh%B
    int t = threadIdx.x, lane = t & 63, w = t >> 6;
    int hi = lane >> 5, ql = lane & 31;
    int q0 = qb * 128 + w * 32;
    const unsigned short* Qp = Q + (size_t)bh * SEQ * DHEAD;
    const unsigned short* Kp = Kg + (size_t)bh * SEQ * DHEAD;   // fragment layout
    const unsigned short* Vg = Vt + (size_t)bh * SEQ * DHEAD;   // fragment layout
    const unsigned long long* mw = mwords + mb * 32;
    const unsigned short* Mv = maskvb + mb * SEQ;

    // full-range fully-masked detection (uniform scalar loads)
    unsigned long long anyb = 0ull;
#pragma unroll
    for (int i = 0; i < 32; i++) anyb |= mw[i];

    bf16x8 qf[4];
#pragma unroll
    for (int c = 0; c < 4; c++)
        qf[c] = *(const bf16x8*)&Qp[(size_t)(q0 + ql) * DHEAD + c * 16 + hi * 8];

    f32x16 Y0 = {}, Y1 = {}, Yl = {};
    float m_ = -1e30f;
    const float LOG2E = 1.442695041f;

    for (int tt0 = 0; tt0 < 32; tt0++) {
        // K fragments: coalesced global loads (frag = c*2+hi, rows ql / 32+ql)
        const unsigned short* kt = &Kp[(size_t)tt0 * 4096];
        bf16x8 kf0[4], kf1[4];
#pragma unroll
        for (int c = 0; c < 4; c++) {
            kf0[c] = *(const bf16x8*)&kt[(size_t)((c * 2 + hi) * 64 + ql) * 8];
            kf1[c] = *(const bf16x8*)&kt[(size_t)((c * 2 + hi) * 64 + 32 + ql) * 8];
        }
        // V fragments + mask indicator rows
        const unsigned short* vt = &Vg[(size_t)tt0 * 4096];
        bf16x8 vb0[4], vb1[4], im[4];
#pragma unroll
        for (int ks = 0; ks < 4; ks++) {
            vb0[ks] = *(const bf16x8*)&vt[(size_t)((ks * 2 + hi) * 64 + ql) * 8];
            vb1[ks] = *(const bf16x8*)&vt[(size_t)((ks * 2 + hi) * 64 + 32 + ql) * 8];
            im[ks]  = *(const bf16x8*)&Mv[tt0 * 64 + 16 * ks + 8 * hi];
        }

        // QK^T swapped: S[k][q]
        f32x16 S0 = {}, S1 = {};
        __builtin_amdgcn_s_setprio(1);
#pragma unroll
        for (int c = 0; c < 4; c++) S0 = mfma32(kf0[c], qf[c], S0);
#pragma unroll
        for (int c = 0; c < 4; c++) S1 = mfma32(kf1[c], qf[c], S1);
        __builtin_amdgcn_s_setprio(0);

        // in-lane max tree over 32 raw scores (masked included: valid shift)
        float t0[16];
#pragma unroll
        for (int r = 0; r < 16; r++) t0[r] = fmaxf(S0[r], S1[r]);
#pragma unroll
        for (int s = 8; s > 0; s >>= 1)
#pragma unroll
            for (int r = 0; r < 8; r++)
                if (r < s) t0[r] = fmaxf(t0[r], t0[r + s]);

        // defer-max: __all over both halves == cross-half max test;
        // shfl only inside the rare rescale branch
        if (!__all(t0[0] <= m_ + 8.0f)) {
            float pmax = fmaxf(t0[0], __shfl_xor(t0[0], 32, 64));
            float mnew = fmaxf(m_, pmax);
            float al = __expf(m_ - mnew);
            m_ = mnew;
#pragma unroll
            for (int reg = 0; reg < 16; reg++) {
                float av = __shfl(al, (reg & 3) + 8 * (reg >> 2) + 4 * hi, 64);
                Y0[reg] *= av;
                Y1[reg] *= av;
                Yl[reg] *= av;
            }
        }

        // p = exp2(fma(S, log2e, -m*log2e)) -- masking & sums handled by MFMA
        float nmL = -m_ * LOG2E;
        float p[32];
#pragma unroll
        for (int rr = 0; rr < 16; rr++) p[rr] = fexp2(fmaf(S0[rr], LOG2E, nmL));
#pragma unroll
        for (int rr = 0; rr < 16; rr++) p[16 + rr] = fexp2(fmaf(S1[rr], LOG2E, nmL));

        // pack P -> bf16 pairs (own blocks only)
        unsigned PKa[8], PKb[8];
#pragma unroll
        for (int i = 0; i < 8; i++) {
            PKa[i] = cvtpk(p[4 * i], p[4 * i + 1]);
            PKb[i] = cvtpk(p[4 * i + 2], p[4 * i + 3]);
        }

        // exchange-free A-fragments via permuted inner-k
        bf16x8 pa[4];
#pragma unroll
        for (int ks = 0; ks < 4; ks++) {
            union { unsigned u[4]; bf16x8 v; } pu;
            pu.u[0] = PKa[2 * ks];
            pu.u[1] = PKb[2 * ks];
            pu.u[2] = PKa[2 * ks + 1];
            pu.u[3] = PKb[2 * ks + 1];
            pa[ks] = pu.v;
        }

        // PV (V masked-zero in memory) + indicator-MFMA for l
        __builtin_amdgcn_s_setprio(1);
#pragma unroll
        for (int ks = 0; ks < 4; ks++) {
            Y0 = mfma32(pa[ks], vb0[ks], Y0);
            Y1 = mfma32(pa[ks], vb1[ks], Y1);
            Yl = mfma32(pa[ks], im[ks],  Yl);
        }
        __builtin_amdgcn_s_setprio(0);
    }

    // ---- epilogue: normalize and store (Yl[reg] = row sum l for that q-row) ----
#pragma unroll
    for (int reg = 0; reg < 16; reg++) {
        float lv = (anyb != 0ull) ? (1.0f / Yl[reg]) : 0.f;
        int row = (reg & 3) + 8 * (reg >> 2) + 4 * hi;
        int n = q0 + row;
        size_t base = ((size_t)b * SEQ + n) * DMODEL + h * DHEAD;
        Zt[base + ql] = f2bf(Y0[reg] * lv);
        Zt[base + 32 + ql] = f2bf(Y1[reg] * lv);
    }
}

extern "C" void kernel_launch(void* const* d_in, const int* in_sizes, int n_in,
                              void* d_out, int out_size, void* d_ws, size_t ws_size,
                              hipStream_t stream) {
    const float* query = (const float*)d_in[0];
    const float* Wq = (const float*)d_in[1];
    const float* bq = (const float*)d_in[2];
    const float* Wk = (const float*)d_in[3];
    const float* bk = (const float*)d_in[4];
    const float* Wv = (const float*)d_in[5];
    const float* bv = (const float*)d_in[6];
    const float* Wo = (const float*)d_in[7];
    const float* bo = (const float*)d_in[8];
    const int* mask = (const int*)d_in[9];
    float* out = (float*)d_out;

    char* ws = (char*)d_ws;
    unsigned short* Wb  = (unsigned short*)(ws);                      // 8MB (Wq|Wk|Wv|Wo)
    unsigned short* Xt  = (unsigned short*)(ws + ((size_t)8  << 20)); // 8MB
    unsigned short* Qb  = (unsigned short*)(ws + ((size_t)16 << 20)); // 8MB
    unsigned short* Kbuf= (unsigned short*)(ws + ((size_t)24 << 20)); // 8MB (fragment layout)
    unsigned short* Vtb = (unsigned short*)(ws + ((size_t)32 << 20)); // 8MB (fragment layout)
    unsigned short* Zt  = (unsigned short*)(ws + ((size_t)40 << 20)); // 8MB
    unsigned long long* mwords = (unsigned long long*)(ws + ((size_t)48 << 20)); // 512B
    unsigned short* maskvb = (unsigned short*)(ws + ((size_t)48 << 20) + 65536); // 8KB

    const size_t WSZ = (size_t)DMODEL * DMODEL;

    cvt_w<<<dim3(DMODEL * DMODEL / 1024, 4), 256, 0, stream>>>(Wq, Wk, Wv, Wo, Wb);
    prep_mask<<<64, 64, 0, stream>>>(mask, mwords, maskvb);
    transpose_q<<<dim3(SEQ / 32, DMODEL / 32, BATCH), dim3(32, 8), 0, stream>>>(query, Xt);

    gemm_qkv<<<dim3(3 * DMODEL / 128, COLS / 128), 256, 0, stream>>>(
        Xt, Wb, bq, bk, bv, mask, Qb, Kbuf, Vtb);

    attn<<<512, 256, 0, stream>>>(Qb, Kbuf, Vtb, mwords, maskvb, Zt);

    gemm_out<<<dim3(COLS / 64, DMODEL / 128), 256, 0, stream>>>(
        Wb + 3 * WSZ, Zt, bo, out);
}

// Round 19
// 145.731 us; speedup vs baseline: 1.0758x; 1.0758x over previous
//
#include <hip/hip_runtime.h>
#include <hip/hip_bf16.h>

// B=2, D=1024, N=2048, H=16, DH=64
#define BATCH 2
#define DMODEL 1024
#define SEQ 2048
#define NHEAD 16
#define DHEAD 64
#define BH (BATCH*NHEAD)   // 32
#define COLS (BATCH*SEQ)   // 4096

typedef __attribute__((ext_vector_type(8))) short bf16x8;
typedef __attribute__((ext_vector_type(4))) float f32x4;
typedef __attribute__((ext_vector_type(16))) float f32x16;

__device__ inline unsigned short f2bf(float f) {
    unsigned u = __builtin_bit_cast(unsigned, f);
    unsigned r = (u + 0x7FFFu + ((u >> 16) & 1u)) >> 16;
    return (unsigned short)r;
}

__device__ inline f32x4 mfma16(bf16x8 a, bf16x8 b, f32x4 c) {
    return __builtin_amdgcn_mfma_f32_16x16x32_bf16(a, b, c, 0, 0, 0);
}
__device__ inline f32x16 mfma32(bf16x8 a, bf16x8 b, f32x16 c) {
    return __builtin_amdgcn_mfma_f32_32x32x16_bf16(a, b, c, 0, 0, 0);
}

__device__ __forceinline__ void gload_lds16(const unsigned short* g, unsigned short* l) {
    __builtin_amdgcn_global_load_lds(
        (const __attribute__((address_space(1))) unsigned int*)g,
        (__attribute__((address_space(3))) unsigned int*)l, 16, 0, 0);
}

__device__ inline unsigned cvtpk(float lo, float hi) {
    unsigned r;
    asm("v_cvt_pk_bf16_f32 %0, %1, %2" : "=v"(r) : "v"(lo), "v"(hi));
    return r;
}
__device__ inline float fexp2(float x) {
    float r;
    asm("v_exp_f32 %0, %1" : "=v"(r) : "v"(x));
    return r;
}

// ---------------- convert 4 weight matrices fp32 -> bf16 ----------------
__global__ __launch_bounds__(256) void cvt_w(
    const float* __restrict__ w0, const float* __restrict__ w1,
    const float* __restrict__ w2, const float* __restrict__ w3,
    unsigned short* __restrict__ out)
{
    int which = blockIdx.y;
    const float* src = (which == 0) ? w0 : (which == 1) ? w1 : (which == 2) ? w2 : w3;
    size_t base = (size_t)which * (DMODEL * DMODEL);
    size_t i = ((size_t)blockIdx.x * 256 + threadIdx.x) * 4;
    float4 v = *(const float4*)&src[i];
    ushort4 o;
    o.x = f2bf(v.x); o.y = f2bf(v.y); o.z = f2bf(v.z); o.w = f2bf(v.w);
    *(ushort4*)&out[base + i] = o;
}

// ---------------- mask -> ballot words + permuted bf16 indicator rows ----------------
__global__ __launch_bounds__(64) void prep_mask(
    const int* __restrict__ mask, unsigned long long* __restrict__ mw,
    unsigned short* __restrict__ maskvb)
{
    int lane = threadIdx.x;
    int tile = blockIdx.x;            // [0,64): mb = tile>>5, tt = tile&31
    int mb = tile >> 5, tt = tile & 31;
    int mv = mask[mb * SEQ + tt * 64 + lane];
    unsigned long long bits = __ballot(mv != 0);
    if (lane == 0) mw[tile] = bits;
    // quartet-permuted indicator (same permute as V storage)
    int q2 = (lane >> 2) & 3;
    int q2s = ((q2 & 1) << 1) | (q2 >> 1);   // 0->0, 1->2, 2->1, 3->3
    int pp = (lane & ~15) | (q2s << 2) | (lane & 3);
    maskvb[mb * SEQ + tt * 64 + pp] = mv ? 0x3F80 : 0;   // bf16 1.0 / 0.0
}

// ---------------- transpose query [B][D][N] fp32 -> Xt [B][N][D] bf16 ----------------
__global__ __launch_bounds__(256) void transpose_q(
    const float* __restrict__ q, unsigned short* __restrict__ Xt)
{
    __shared__ float tile[32][33];
    int b = blockIdx.z;
    int d0 = blockIdx.y * 32, n0 = blockIdx.x * 32;
    int tx = threadIdx.x, ty = threadIdx.y;  // 32 x 8
#pragma unroll
    for (int i = 0; i < 32; i += 8)
        tile[ty + i][tx] = q[(size_t)b * DMODEL * SEQ + (size_t)(d0 + ty + i) * SEQ + n0 + tx];
    __syncthreads();
#pragma unroll
    for (int i = 0; i < 32; i += 8)
        Xt[(size_t)b * SEQ * DMODEL + (size_t)(n0 + ty + i) * DMODEL + d0 + tx] = f2bf(tile[tx][ty + i]);
}

// ---------------- K repack: [bh][n][64] -> Kg[bh][tile 32][frag 8][k 64][8] ----------------
// Kg[bh][tl][f][r][j] = K[bh][tl*64+r][f*8+j]: writes perfectly coalesced 16B,
// reads 16B contiguous at 128B stride (cached, no RMW).
__global__ __launch_bounds__(256) void repack_k(
    const unsigned short* __restrict__ in, unsigned short* __restrict__ out)
{
    int blk = blockIdx.x;             // bh*32 + tl  (1024 blocks)
    size_t base = (size_t)blk * 4096;
    int t = threadIdx.x;
#pragma unroll
    for (int i = 0; i < 2; i++) {
        int c = t + i * 256;          // chunk [0,512): f = c>>6, r = c&63
        int f = c >> 6, r = c & 63;
        *(uint4*)&out[base + (size_t)c * 8] =
            *(const uint4*)&in[base + (size_t)r * 64 + f * 8];
    }
}

// ---------------- fused QKV GEMM, m97 128x128 structure ----------------
// Q,K row-major per head; V stored PRE-FRAGMENTED (quartet-permuted, masked-zero).
__global__ __launch_bounds__(256) void gemm_qkv(
    const unsigned short* __restrict__ Xt,   // [4096][1024]
    const unsigned short* __restrict__ W3,   // [3072][1024]
    const float* __restrict__ bq, const float* __restrict__ bk, const float* __restrict__ bv,
    const int* __restrict__ mask,
    unsigned short* __restrict__ Qb, unsigned short* __restrict__ Kbuf,
    unsigned short* __restrict__ Vtb)
{
    const int K = DMODEL;
    __shared__ unsigned short sA[128 * 32];
    __shared__ unsigned short sB[128 * 32];
    int t = threadIdx.x, lane = t & 63, w = t >> 6;
    int wr = w >> 1, wc = w & 1;
    int tt0 = blockIdx.y * 128;        // token tile
    int ct0 = blockIdx.x * 128;        // e tile within stacked 3072
    int mat = ct0 >> 10, ec0 = ct0 & 1023;
    const float* bs = (mat == 0) ? bq : (mat == 1) ? bk : bv;
    int rl = lane & 15, ko = (lane >> 4) << 3;
    int srow = lane >> 2, scol = (lane & 3) << 3;

    f32x4 acc[4][4] = {};
    for (int kb = 0; kb < K; kb += 32) {
        __syncthreads();
        gload_lds16(&Xt[(size_t)(tt0 + w * 32 + srow) * K + kb + scol],      &sA[(w * 32) * 32]);
        gload_lds16(&Xt[(size_t)(tt0 + w * 32 + 16 + srow) * K + kb + scol], &sA[(w * 32 + 16) * 32]);
        gload_lds16(&W3[(size_t)(ct0 + w * 32 + srow) * K + kb + scol],      &sB[(w * 32) * 32]);
        gload_lds16(&W3[(size_t)(ct0 + w * 32 + 16 + srow) * K + kb + scol], &sB[(w * 32 + 16) * 32]);
        __syncthreads();
        bf16x8 af[4], bfr[4];
#pragma unroll
        for (int m = 0; m < 4; m++)
            af[m] = *(const bf16x8*)&sA[(wr * 64 + m * 16 + rl) * 32 + ko];
#pragma unroll
        for (int n = 0; n < 4; n++)
            bfr[n] = *(const bf16x8*)&sB[(wc * 64 + n * 16 + rl) * 32 + ko];
#pragma unroll
        for (int m = 0; m < 4; m++)
#pragma unroll
            for (int n = 0; n < 4; n++)
                acc[m][n] = mfma16(af[m], bfr[n], acc[m][n]);
    }

    const float QS = 0.125f;   // exact power of two
    int rowb = (lane >> 4) * 4, col = lane & 15;
#pragma unroll
    for (int m = 0; m < 4; m++) {
#pragma unroll
        for (int n = 0; n < 4; n++) {
            int ee = ec0 + wc * 64 + n * 16 + col;
            int hh = ee >> 6, dd = ee & 63;
            float bias = bs[ee];
#pragma unroll
            for (int r = 0; r < 4; r++) {
                int tk = tt0 + wr * 64 + m * 16 + rowb + r;
                int b = tk >> 11, nn = tk & (SEQ - 1);
                float v = acc[m][n][r] + bias;
                if (mat == 0) {
                    v *= QS;
                    Qb[((size_t)(b * NHEAD + hh) * SEQ + nn) * DHEAD + dd] = f2bf(v);
                } else if (mat == 1) {
                    Kbuf[((size_t)(b * NHEAD + hh) * SEQ + nn) * DHEAD + dd] = f2bf(v);
                } else {
                    // zero masked keys; quartet permute; store into fragment layout
                    if (mask[(hh & 1) * SEQ + nn] == 0) v = 0.f;
                    int q2 = (nn >> 2) & 3;
                    int q2s = ((q2 & 1) << 1) | (q2 >> 1);   // 0->0, 1->2, 2->1, 3->3
                    int np = (nn & ~15) | (q2s << 2) | (nn & 3);
                    int tl = np >> 6, kk = np & 63;
                    int ks = kk >> 4, hi2 = (kk >> 3) & 1, jj = kk & 7;
                    Vtb[((((size_t)(b * NHEAD + hh) * 32 + tl) * 8 + ks * 2 + hi2) * 64 + dd) * 8 + jj] = f2bf(v);
                }
            }
        }
    }
}

// ---------------- output GEMM: out[e,c] = sum_d Wo[e,d]*Zt[c,d] + bo[e] ----------------
__global__ __launch_bounds__(256) void gemm_out(
    const unsigned short* __restrict__ A,    // Wo bf16 [1024][1024]
    const unsigned short* __restrict__ Bt,   // Zt [4096][1024]
    const float* __restrict__ bias,
    float* __restrict__ outf)
{
    const int K = DMODEL;
    __shared__ unsigned short sA[128 * 32];
    __shared__ unsigned short sB[64 * 32];
    int t = threadIdx.x, lane = t & 63, w = t >> 6;
    int wr = w >> 1, wc = w & 1;
    int et0 = blockIdx.y * 128, ct0 = blockIdx.x * 64;
    int rl = lane & 15, ko = (lane >> 4) << 3;
    int srow = lane >> 2, scol = (lane & 3) << 3;

    f32x4 acc[4][2] = {};
    for (int kb = 0; kb < K; kb += 32) {
        __syncthreads();
        gload_lds16(&A[(size_t)(et0 + w * 16 + srow) * K + kb + scol],      &sA[(w * 16) * 32]);
        gload_lds16(&A[(size_t)(et0 + 64 + w * 16 + srow) * K + kb + scol], &sA[(64 + w * 16) * 32]);
        gload_lds16(&Bt[(size_t)(ct0 + w * 16 + srow) * K + kb + scol],     &sB[(w * 16) * 32]);
        __syncthreads();
        bf16x8 af[4], bfr[2];
#pragma unroll
        for (int m = 0; m < 4; m++)
            af[m] = *(const bf16x8*)&sA[(wr * 64 + m * 16 + rl) * 32 + ko];
#pragma unroll
        for (int n = 0; n < 2; n++)
            bfr[n] = *(const bf16x8*)&sB[(wc * 32 + n * 16 + rl) * 32 + ko];
#pragma unroll
        for (int m = 0; m < 4; m++)
#pragma unroll
            for (int n = 0; n < 2; n++)
                acc[m][n] = mfma16(af[m], bfr[n], acc[m][n]);
    }

    int rowb = (lane >> 4) * 4, col = lane & 15;
#pragma unroll
    for (int m = 0; m < 4; m++) {
#pragma unroll
        for (int n = 0; n < 2; n++) {
            int c = ct0 + wc * 32 + n * 16 + col;
            int b = c >> 11, nn = c & (SEQ - 1);
#pragma unroll
            for (int r = 0; r < 4; r++) {
                int e = et0 + wr * 64 + m * 16 + rowb + r;
                outf[((size_t)b * DMODEL + e) * SEQ + nn] = acc[m][n][r] + bias[e];
            }
        }
    }
}

// ---------------- attention: barrier-free, all operands coalesced from global ----------------
// K (via repack_k) and V both pre-fragmented: per tile, 8 K-loads + 8 V-loads +
// 4 mask-loads (all dwordx4, L2-resident), 20 MFMA, in-register softmax.
// No LDS, no __syncthreads: waves independent, compiler free to pipeline.
__global__ __launch_bounds__(256) void attn(
    const unsigned short* __restrict__ Q,
    const unsigned short* __restrict__ Kg,
    const unsigned short* __restrict__ Vt,
    const unsigned long long* __restrict__ mwords,
    const unsigned short* __restrict__ maskvb,
    unsigned short* __restrict__ Zt)
{
    int bid = blockIdx.x;                 // 512 blocks; bid%8 -> XCD
    int xcd = bid & 7, slot = bid >> 3;
    int bh = xcd + 8 * (slot >> 4);       // 4 heads per XCD
    int qb = slot & 15;
    int b = bh >> 4, h = bh & 15;
    int mb = bh & (BATCH - 1);            // tile semantics: head bh uses mask row bh%B
    int t = threadIdx.x, lane = t & 63, w = t >> 6;
    int hi = lane >> 5, ql = lane & 31;
    int q0 = qb * 128 + w * 32;
    const unsigned short* Qp = Q + (size_t)bh * SEQ * DHEAD;
    const unsigned short* Kp = Kg + (size_t)bh * SEQ * DHEAD;   // fragment layout
    const unsigned short* Vg = Vt + (size_t)bh * SEQ * DHEAD;   // fragment layout
    const unsigned long long* mw = mwords + mb * 32;
    const unsigned short* Mv = maskvb + mb * SEQ;

    // full-range fully-masked detection (uniform scalar loads)
    unsigned long long anyb = 0ull;
#pragma unroll
    for (int i = 0; i < 32; i++) anyb |= mw[i];

    bf16x8 qf[4];
#pragma unroll
    for (int c = 0; c < 4; c++)
        qf[c] = *(const bf16x8*)&Qp[(size_t)(q0 + ql) * DHEAD + c * 16 + hi * 8];

    f32x16 Y0 = {}, Y1 = {}, Yl = {};
    float m_ = -1e30f;
    const float LOG2E = 1.442695041f;

    for (int tt0 = 0; tt0 < 32; tt0++) {
        // K fragments: coalesced global loads (frag = c*2+hi, rows ql / 32+ql)
        const unsigned short* kt = &Kp[(size_t)tt0 * 4096];
        bf16x8 kf0[4], kf1[4];
#pragma unroll
        for (int c = 0; c < 4; c++) {
            kf0[c] = *(const bf16x8*)&kt[(size_t)((c * 2 + hi) * 64 + ql) * 8];
            kf1[c] = *(const bf16x8*)&kt[(size_t)((c * 2 + hi) * 64 + 32 + ql) * 8];
        }
        // V fragments + mask indicator rows
        const unsigned short* vt = &Vg[(size_t)tt0 * 4096];
        bf16x8 vb0[4], vb1[4], im[4];
#pragma unroll
        for (int ks = 0; ks < 4; ks++) {
            vb0[ks] = *(const bf16x8*)&vt[(size_t)((ks * 2 + hi) * 64 + ql) * 8];
            vb1[ks] = *(const bf16x8*)&vt[(size_t)((ks * 2 + hi) * 64 + 32 + ql) * 8];
            im[ks]  = *(const bf16x8*)&Mv[tt0 * 64 + 16 * ks + 8 * hi];
        }

        // QK^T swapped: S[k][q]
        f32x16 S0 = {}, S1 = {};
        __builtin_amdgcn_s_setprio(1);
#pragma unroll
        for (int c = 0; c < 4; c++) S0 = mfma32(kf0[c], qf[c], S0);
#pragma unroll
        for (int c = 0; c < 4; c++) S1 = mfma32(kf1[c], qf[c], S1);
        __builtin_amdgcn_s_setprio(0);

        // in-lane max tree over 32 raw scores (masked included: valid shift)
        float t0[16];
#pragma unroll
        for (int r = 0; r < 16; r++) t0[r] = fmaxf(S0[r], S1[r]);
#pragma unroll
        for (int s = 8; s > 0; s >>= 1)
#pragma unroll
            for (int r = 0; r < 8; r++)
                if (r < s) t0[r] = fmaxf(t0[r], t0[r + s]);

        // defer-max: __all over both halves == cross-half max test;
        // shfl only inside the rare rescale branch
        if (!__all(t0[0] <= m_ + 8.0f)) {
            float pmax = fmaxf(t0[0], __shfl_xor(t0[0], 32, 64));
            float mnew = fmaxf(m_, pmax);
            float al = __expf(m_ - mnew);
            m_ = mnew;
#pragma unroll
            for (int reg = 0; reg < 16; reg++) {
                float av = __shfl(al, (reg & 3) + 8 * (reg >> 2) + 4 * hi, 64);
                Y0[reg] *= av;
                Y1[reg] *= av;
                Yl[reg] *= av;
            }
        }

        // p = exp2(fma(S, log2e, -m*log2e)) -- masking & sums handled by MFMA
        float nmL = -m_ * LOG2E;
        float p[32];
#pragma unroll
        for (int rr = 0; rr < 16; rr++) p[rr] = fexp2(fmaf(S0[rr], LOG2E, nmL));
#pragma unroll
        for (int rr = 0; rr < 16; rr++) p[16 + rr] = fexp2(fmaf(S1[rr], LOG2E, nmL));

        // pack P -> bf16 pairs (own blocks only)
        unsigned PKa[8], PKb[8];
#pragma unroll
        for (int i = 0; i < 8; i++) {
            PKa[i] = cvtpk(p[4 * i], p[4 * i + 1]);
            PKb[i] = cvtpk(p[4 * i + 2], p[4 * i + 3]);
        }

        // exchange-free A-fragments via permuted inner-k
        bf16x8 pa[4];
#pragma unroll
        for (int ks = 0; ks < 4; ks++) {
            union { unsigned u[4]; bf16x8 v; } pu;
            pu.u[0] = PKa[2 * ks];
            pu.u[1] = PKb[2 * ks];
            pu.u[2] = PKa[2 * ks + 1];
            pu.u[3] = PKb[2 * ks + 1];
            pa[ks] = pu.v;
        }

        // PV (V masked-zero in memory) + indicator-MFMA for l
        __builtin_amdgcn_s_setprio(1);
#pragma unroll
        for (int ks = 0; ks < 4; ks++) {
            Y0 = mfma32(pa[ks], vb0[ks], Y0);
            Y1 = mfma32(pa[ks], vb1[ks], Y1);
            Yl = mfma32(pa[ks], im[ks],  Yl);
        }
        __builtin_amdgcn_s_setprio(0);
    }

    // ---- epilogue: normalize and store (Yl[reg] = row sum l for that q-row) ----
#pragma unroll
    for (int reg = 0; reg < 16; reg++) {
        float lv = (anyb != 0ull) ? (1.0f / Yl[reg]) : 0.f;
        int row = (reg & 3) + 8 * (reg >> 2) + 4 * hi;
        int n = q0 + row;
        size_t base = ((size_t)b * SEQ + n) * DMODEL + h * DHEAD;
        Zt[base + ql] = f2bf(Y0[reg] * lv);
        Zt[base + 32 + ql] = f2bf(Y1[reg] * lv);
    }
}

extern "C" void kernel_launch(void* const* d_in, const int* in_sizes, int n_in,
                              void* d_out, int out_size, void* d_ws, size_t ws_size,
                              hipStream_t stream) {
    const float* query = (const float*)d_in[0];
    const float* Wq = (const float*)d_in[1];
    const float* bq = (const float*)d_in[2];
    const float* Wk = (const float*)d_in[3];
    const float* bk = (const float*)d_in[4];
    const float* Wv = (const float*)d_in[5];
    const float* bv = (const float*)d_in[6];
    const float* Wo = (const float*)d_in[7];
    const float* bo = (const float*)d_in[8];
    const int* mask = (const int*)d_in[9];
    float* out = (float*)d_out;

    char* ws = (char*)d_ws;
    unsigned short* Wb  = (unsigned short*)(ws);                      // 8MB (Wq|Wk|Wv|Wo)
    unsigned short* Xt  = (unsigned short*)(ws + ((size_t)8  << 20)); // 8MB (-> Kg after gemm)
    unsigned short* Qb  = (unsigned short*)(ws + ((size_t)16 << 20)); // 8MB
    unsigned short* Kbuf= (unsigned short*)(ws + ((size_t)24 << 20)); // 8MB (row layout)
    unsigned short* Vtb = (unsigned short*)(ws + ((size_t)32 << 20)); // 8MB (fragment layout)
    unsigned short* Zt  = (unsigned short*)(ws + ((size_t)40 << 20)); // 8MB
    unsigned long long* mwords = (unsigned long long*)(ws + ((size_t)48 << 20)); // 512B
    unsigned short* maskvb = (unsigned short*)(ws + ((size_t)48 << 20) + 65536); // 8KB
    unsigned short* Kg = Xt;   // Xt dead after gemm_qkv; reuse for K fragment layout

    const size_t WSZ = (size_t)DMODEL * DMODEL;

    cvt_w<<<dim3(DMODEL * DMODEL / 1024, 4), 256, 0, stream>>>(Wq, Wk, Wv, Wo, Wb);
    prep_mask<<<64, 64, 0, stream>>>(mask, mwords, maskvb);
    transpose_q<<<dim3(SEQ / 32, DMODEL / 32, BATCH), dim3(32, 8), 0, stream>>>(query, Xt);

    gemm_qkv<<<dim3(3 * DMODEL / 128, COLS / 128), 256, 0, stream>>>(
        Xt, Wb, bq, bk, bv, mask, Qb, Kbuf, Vtb);

    repack_k<<<BH * 32, 256, 0, stream>>>(Kbuf, Kg);

    attn<<<512, 256, 0, stream>>>(Qb, Kg, Vtb, mwords, maskvb, Zt);

    gemm_out<<<dim3(COLS / 64, DMODEL / 128), 256, 0, stream>>>(
        Wb + 3 * WSZ, Zt, bo, out);
}

// Round 20
// 136.467 us; speedup vs baseline: 1.1488x; 1.0679x over previous
//
#include <hip/hip_runtime.h>
#include <hip/hip_bf16.h>

// B=2, D=1024, N=2048, H=16, DH=64
#define BATCH 2
#define DMODEL 1024
#define SEQ 2048
#define NHEAD 16
#define DHEAD 64
#define BH (BATCH*NHEAD)   // 32
#define COLS (BATCH*SEQ)   // 4096

typedef __attribute__((ext_vector_type(8))) short bf16x8;
typedef __attribute__((ext_vector_type(4))) float f32x4;
typedef __attribute__((ext_vector_type(16))) float f32x16;

__device__ inline unsigned short f2bf(float f) {
    unsigned u = __builtin_bit_cast(unsigned, f);
    unsigned r = (u + 0x7FFFu + ((u >> 16) & 1u)) >> 16;
    return (unsigned short)r;
}

__device__ inline f32x4 mfma16(bf16x8 a, bf16x8 b, f32x4 c) {
    return __builtin_amdgcn_mfma_f32_16x16x32_bf16(a, b, c, 0, 0, 0);
}
__device__ inline f32x16 mfma32(bf16x8 a, bf16x8 b, f32x16 c) {
    return __builtin_amdgcn_mfma_f32_32x32x16_bf16(a, b, c, 0, 0, 0);
}

__device__ __forceinline__ void gload_lds16(const unsigned short* g, unsigned short* l) {
    __builtin_amdgcn_global_load_lds(
        (const __attribute__((address_space(1))) unsigned int*)g,
        (__attribute__((address_space(3))) unsigned int*)l, 16, 0, 0);
}

__device__ inline unsigned cvtpk(float lo, float hi) {
    unsigned r;
    asm("v_cvt_pk_bf16_f32 %0, %1, %2" : "=v"(r) : "v"(lo), "v"(hi));
    return r;
}
__device__ inline float fexp2(float x) {
    float r;
    asm("v_exp_f32 %0, %1" : "=v"(r) : "v"(x));
    return r;
}

// ---------------- convert 4 weight matrices fp32 -> bf16 ----------------
__global__ __launch_bounds__(256) void cvt_w(
    const float* __restrict__ w0, const float* __restrict__ w1,
    const float* __restrict__ w2, const float* __restrict__ w3,
    unsigned short* __restrict__ out)
{
    int which = blockIdx.y;
    const float* src = (which == 0) ? w0 : (which == 1) ? w1 : (which == 2) ? w2 : w3;
    size_t base = (size_t)which * (DMODEL * DMODEL);
    size_t i = ((size_t)blockIdx.x * 256 + threadIdx.x) * 4;
    float4 v = *(const float4*)&src[i];
    ushort4 o;
    o.x = f2bf(v.x); o.y = f2bf(v.y); o.z = f2bf(v.z); o.w = f2bf(v.w);
    *(ushort4*)&out[base + i] = o;
}

// ---------------- mask -> ballot words + permuted bf16 indicator rows ----------------
__global__ __launch_bounds__(64) void prep_mask(
    const int* __restrict__ mask, unsigned long long* __restrict__ mw,
    unsigned short* __restrict__ maskvb)
{
    int lane = threadIdx.x;
    int tile = blockIdx.x;            // [0,64): mb = tile>>5, tt = tile&31
    int mb = tile >> 5, tt = tile & 31;
    int mv = mask[mb * SEQ + tt * 64 + lane];
    unsigned long long bits = __ballot(mv != 0);
    if (lane == 0) mw[tile] = bits;
    // quartet-permuted indicator (same permute as V storage)
    int q2 = (lane >> 2) & 3;
    int q2s = ((q2 & 1) << 1) | (q2 >> 1);   // 0->0, 1->2, 2->1, 3->3
    int pp = (lane & ~15) | (q2s << 2) | (lane & 3);
    maskvb[mb * SEQ + tt * 64 + pp] = mv ? 0x3F80 : 0;   // bf16 1.0 / 0.0
}

// ---------------- transpose query [B][D][N] fp32 -> Xt [B][N][D] bf16 ----------------
__global__ __launch_bounds__(256) void transpose_q(
    const float* __restrict__ q, unsigned short* __restrict__ Xt)
{
    __shared__ float tile[32][33];
    int b = blockIdx.z;
    int d0 = blockIdx.y * 32, n0 = blockIdx.x * 32;
    int tx = threadIdx.x, ty = threadIdx.y;  // 32 x 8
#pragma unroll
    for (int i = 0; i < 32; i += 8)
        tile[ty + i][tx] = q[(size_t)b * DMODEL * SEQ + (size_t)(d0 + ty + i) * SEQ + n0 + tx];
    __syncthreads();
#pragma unroll
    for (int i = 0; i < 32; i += 8)
        Xt[(size_t)b * SEQ * DMODEL + (size_t)(n0 + ty + i) * DMODEL + d0 + tx] = f2bf(tile[tx][ty + i]);
}

// ---------------- fused QKV GEMM, m97 128x128 structure ----------------
// V stored PRE-FRAGMENTED: Vg[bh][tile 32][frag 8 = ks*2+hi][d 64][8 bf16],
// quartet-permuted within each 16-key group and ZEROED at masked keys.
__global__ __launch_bounds__(256) void gemm_qkv(
    const unsigned short* __restrict__ Xt,   // [4096][1024]
    const unsigned short* __restrict__ W3,   // [3072][1024]
    const float* __restrict__ bq, const float* __restrict__ bk, const float* __restrict__ bv,
    const int* __restrict__ mask,
    unsigned short* __restrict__ Qb, unsigned short* __restrict__ Kbuf,
    unsigned short* __restrict__ Vtb)
{
    const int K = DMODEL;
    __shared__ unsigned short sA[128 * 32];
    __shared__ unsigned short sB[128 * 32];
    int t = threadIdx.x, lane = t & 63, w = t >> 6;
    int wr = w >> 1, wc = w & 1;
    int tt0 = blockIdx.y * 128;        // token tile
    int ct0 = blockIdx.x * 128;        // e tile within stacked 3072
    int mat = ct0 >> 10, ec0 = ct0 & 1023;
    const float* bs = (mat == 0) ? bq : (mat == 1) ? bk : bv;
    int rl = lane & 15, ko = (lane >> 4) << 3;
    int srow = lane >> 2, scol = (lane & 3) << 3;

    f32x4 acc[4][4] = {};
    for (int kb = 0; kb < K; kb += 32) {
        __syncthreads();
        gload_lds16(&Xt[(size_t)(tt0 + w * 32 + srow) * K + kb + scol],      &sA[(w * 32) * 32]);
        gload_lds16(&Xt[(size_t)(tt0 + w * 32 + 16 + srow) * K + kb + scol], &sA[(w * 32 + 16) * 32]);
        gload_lds16(&W3[(size_t)(ct0 + w * 32 + srow) * K + kb + scol],      &sB[(w * 32) * 32]);
        gload_lds16(&W3[(size_t)(ct0 + w * 32 + 16 + srow) * K + kb + scol], &sB[(w * 32 + 16) * 32]);
        __syncthreads();
        bf16x8 af[4], bfr[4];
#pragma unroll
        for (int m = 0; m < 4; m++)
            af[m] = *(const bf16x8*)&sA[(wr * 64 + m * 16 + rl) * 32 + ko];
#pragma unroll
        for (int n = 0; n < 4; n++)
            bfr[n] = *(const bf16x8*)&sB[(wc * 64 + n * 16 + rl) * 32 + ko];
#pragma unroll
        for (int m = 0; m < 4; m++)
#pragma unroll
            for (int n = 0; n < 4; n++)
                acc[m][n] = mfma16(af[m], bfr[n], acc[m][n]);
    }

    const float QS = 0.125f;   // exact power of two
    int rowb = (lane >> 4) * 4, col = lane & 15;
#pragma unroll
    for (int m = 0; m < 4; m++) {
#pragma unroll
        for (int n = 0; n < 4; n++) {
            int ee = ec0 + wc * 64 + n * 16 + col;
            int hh = ee >> 6, dd = ee & 63;
            float bias = bs[ee];
#pragma unroll
            for (int r = 0; r < 4; r++) {
                int tk = tt0 + wr * 64 + m * 16 + rowb + r;
                int b = tk >> 11, nn = tk & (SEQ - 1);
                float v = acc[m][n][r] + bias;
                if (mat == 0) {
                    v *= QS;
                    Qb[((size_t)(b * NHEAD + hh) * SEQ + nn) * DHEAD + dd] = f2bf(v);
                } else if (mat == 1) {
                    Kbuf[((size_t)(b * NHEAD + hh) * SEQ + nn) * DHEAD + dd] = f2bf(v);
                } else {
                    // zero masked keys; quartet permute; store into fragment layout
                    if (mask[(hh & 1) * SEQ + nn] == 0) v = 0.f;
                    int q2 = (nn >> 2) & 3;
                    int q2s = ((q2 & 1) << 1) | (q2 >> 1);   // 0->0, 1->2, 2->1, 3->3
                    int np = (nn & ~15) | (q2s << 2) | (nn & 3);
                    int tl = np >> 6, kk = np & 63;
                    int ks = kk >> 4, hi2 = (kk >> 3) & 1, jj = kk & 7;
                    Vtb[((((size_t)(b * NHEAD + hh) * 32 + tl) * 8 + ks * 2 + hi2) * 64 + dd) * 8 + jj] = f2bf(v);
                }
            }
        }
    }
}

// ---------------- output GEMM: out[e,c] = sum_d Wo[e,d]*Zt[c,d] + bo[e] ----------------
__global__ __launch_bounds__(256) void gemm_out(
    const unsigned short* __restrict__ A,    // Wo bf16 [1024][1024]
    const unsigned short* __restrict__ Bt,   // Zt [4096][1024]
    const float* __restrict__ bias,
    float* __restrict__ outf)
{
    const int K = DMODEL;
    __shared__ unsigned short sA[128 * 32];
    __shared__ unsigned short sB[64 * 32];
    int t = threadIdx.x, lane = t & 63, w = t >> 6;
    int wr = w >> 1, wc = w & 1;
    int et0 = blockIdx.y * 128, ct0 = blockIdx.x * 64;
    int rl = lane & 15, ko = (lane >> 4) << 3;
    int srow = lane >> 2, scol = (lane & 3) << 3;

    f32x4 acc[4][2] = {};
    for (int kb = 0; kb < K; kb += 32) {
        __syncthreads();
        gload_lds16(&A[(size_t)(et0 + w * 16 + srow) * K + kb + scol],      &sA[(w * 16) * 32]);
        gload_lds16(&A[(size_t)(et0 + 64 + w * 16 + srow) * K + kb + scol], &sA[(64 + w * 16) * 32]);
        gload_lds16(&Bt[(size_t)(ct0 + w * 16 + srow) * K + kb + scol],     &sB[(w * 16) * 32]);
        __syncthreads();
        bf16x8 af[4], bfr[2];
#pragma unroll
        for (int m = 0; m < 4; m++)
            af[m] = *(const bf16x8*)&sA[(wr * 64 + m * 16 + rl) * 32 + ko];
#pragma unroll
        for (int n = 0; n < 2; n++)
            bfr[n] = *(const bf16x8*)&sB[(wc * 32 + n * 16 + rl) * 32 + ko];
#pragma unroll
        for (int m = 0; m < 4; m++)
#pragma unroll
            for (int n = 0; n < 2; n++)
                acc[m][n] = mfma16(af[m], bfr[n], acc[m][n]);
    }

    int rowb = (lane >> 4) * 4, col = lane & 15;
#pragma unroll
    for (int m = 0; m < 4; m++) {
#pragma unroll
        for (int n = 0; n < 2; n++) {
            int c = ct0 + wc * 32 + n * 16 + col;
            int b = c >> 11, nn = c & (SEQ - 1);
#pragma unroll
            for (int r = 0; r < 4; r++) {
                int e = et0 + wr * 64 + m * 16 + rowb + r;
                outf[((size_t)b * DMODEL + e) * SEQ + nn] = acc[m][n][r] + bias[e];
            }
        }
    }
}

// ---------------- attention: K LDS-staged, V coalesced from global fragments ----------------
// R17 configuration (measured best): K via double-buffered swizzled LDS,
// V via coalesced fragment loads, mask via V-zeroing + indicator-MFMA,
// defer-max with shfl only inside the rare rescale branch.
__global__ __launch_bounds__(256, 2) void attn(
    const unsigned short* __restrict__ Q,
    const unsigned short* __restrict__ Kb,
    const unsigned short* __restrict__ Vt,
    const unsigned long long* __restrict__ mwords,
    const unsigned short* __restrict__ maskvb,
    unsigned short* __restrict__ Zt)
{
    __shared__ unsigned short sK[2][64 * 64];   // 8KB x2 (K only)

    int bid = blockIdx.x;                 // 512 blocks; bid%8 -> XCD
    int xcd = bid & 7, slot = bid >> 3;
    int bh = xcd + 8 * (slot >> 4);       // 4 heads per XCD
    int qb = slot & 15;
    int b = bh >> 4, h = bh & 15;
    int mb = bh & (BATCH - 1);            // tile semantics: head bh uses mask row bh%B
    int t = threadIdx.x, lane = t & 63, w = t >> 6;
    int hi = lane >> 5, ql = lane & 31;
    int q0 = qb * 128 + w * 32;
    const unsigned short* Qp = Q + (size_t)bh * SEQ * DHEAD;
    const unsigned short* Kp = Kb + (size_t)bh * SEQ * DHEAD;
    const unsigned short* Vg = Vt + (size_t)bh * SEQ * DHEAD;   // fragment layout
    const unsigned long long* mw = mwords + mb * 32;
    const unsigned short* Mv = maskvb + mb * SEQ;

    // staging geometry: this wave stages rows [w*16, w*16+16) of the K tile.
    int srow0 = w * 16 + (lane >> 3);                    // rows +0..7
    int ssw   = ((lane & 7) ^ ((lane >> 3) & 7)) << 3;   // inverse-swizzled src col (ushorts)

    // full-range fully-masked detection (uniform scalar loads)
    unsigned long long anyb = 0ull;
#pragma unroll
    for (int i = 0; i < 32; i++) anyb |= mw[i];

    bf16x8 qf[4];
#pragma unroll
    for (int c = 0; c < 4; c++)
        qf[c] = *(const bf16x8*)&Qp[(size_t)(q0 + ql) * DHEAD + c * 16 + hi * 8];

    f32x16 Y0 = {}, Y1 = {}, Yl = {};
    float m_ = -1e30f;
    const float LOG2E = 1.442695041f;

    // read-side swizzle offset (ushorts), constant per lane
    int rsw = ql & 7;

    // prologue: stage K tile 0 into buffer 0
    gload_lds16(&Kp[(size_t)srow0 * DHEAD + ssw],       &sK[0][(w * 16) * 64]);
    gload_lds16(&Kp[(size_t)(srow0 + 8) * DHEAD + ssw], &sK[0][(w * 16 + 8) * 64]);
    __syncthreads();

    for (int tt0 = 0; tt0 < 32; tt0++) {
        int cur = tt0 & 1;
        if (tt0 < 31) {
            int kn = (tt0 + 1) * 64;
            gload_lds16(&Kp[(size_t)(kn + srow0) * DHEAD + ssw],     &sK[cur ^ 1][(w * 16) * 64]);
            gload_lds16(&Kp[(size_t)(kn + srow0 + 8) * DHEAD + ssw], &sK[cur ^ 1][(w * 16 + 8) * 64]);
        }

        // V fragments: coalesced global loads (independent pipe)
        const unsigned short* vt = &Vg[(size_t)tt0 * 4096];
        bf16x8 vb0[4], vb1[4], im[4];
#pragma unroll
        for (int ks = 0; ks < 4; ks++) {
            vb0[ks] = *(const bf16x8*)&vt[(size_t)((ks * 2 + hi) * 64 + ql) * 8];
            vb1[ks] = *(const bf16x8*)&vt[(size_t)((ks * 2 + hi) * 64 + 32 + ql) * 8];
            im[ks]  = *(const bf16x8*)&Mv[tt0 * 64 + 16 * ks + 8 * hi];
        }

        // QK^T swapped: S[k][q], K fragments from swizzled LDS
        f32x16 S0 = {}, S1 = {};
        __builtin_amdgcn_s_setprio(1);
#pragma unroll
        for (int c = 0; c < 4; c++) {
            bf16x8 kf = *(const bf16x8*)&sK[cur][ql * 64 + ((((c << 1) | hi) ^ rsw) << 3)];
            S0 = mfma32(kf, qf[c], S0);
        }
#pragma unroll
        for (int c = 0; c < 4; c++) {
            bf16x8 kf = *(const bf16x8*)&sK[cur][(32 + ql) * 64 + ((((c << 1) | hi) ^ rsw) << 3)];
            S1 = mfma32(kf, qf[c], S1);
        }
        __builtin_amdgcn_s_setprio(0);

        // in-lane max tree over 32 raw scores (masked included: valid shift)
        float t0[16];
#pragma unroll
        for (int r = 0; r < 16; r++) t0[r] = fmaxf(S0[r], S1[r]);
#pragma unroll
        for (int s = 8; s > 0; s >>= 1)
#pragma unroll
            for (int r = 0; r < 8; r++)
                if (r < s) t0[r] = fmaxf(t0[r], t0[r + s]);

        // defer-max: __all over both halves == cross-half max test;
        // shfl only inside the rare rescale branch (removes per-tile DS-op)
        if (!__all(t0[0] <= m_ + 8.0f)) {
            float pmax = fmaxf(t0[0], __shfl_xor(t0[0], 32, 64));
            float mnew = fmaxf(m_, pmax);
            float al = __expf(m_ - mnew);
            m_ = mnew;
#pragma unroll
            for (int reg = 0; reg < 16; reg++) {
                float av = __shfl(al, (reg & 3) + 8 * (reg >> 2) + 4 * hi, 64);
                Y0[reg] *= av;
                Y1[reg] *= av;
                Yl[reg] *= av;
            }
        }

        // p = exp2(fma(S, log2e, -m*log2e)) -- masking & sums handled by MFMA
        float nmL = -m_ * LOG2E;
        float p[32];
#pragma unroll
        for (int rr = 0; rr < 16; rr++) p[rr] = fexp2(fmaf(S0[rr], LOG2E, nmL));
#pragma unroll
        for (int rr = 0; rr < 16; rr++) p[16 + rr] = fexp2(fmaf(S1[rr], LOG2E, nmL));

        // pack P -> bf16 pairs (own blocks only)
        unsigned PKa[8], PKb[8];
#pragma unroll
        for (int i = 0; i < 8; i++) {
            PKa[i] = cvtpk(p[4 * i], p[4 * i + 1]);
            PKb[i] = cvtpk(p[4 * i + 2], p[4 * i + 3]);
        }

        // exchange-free A-fragments via permuted inner-k
        bf16x8 pa[4];
#pragma unroll
        for (int ks = 0; ks < 4; ks++) {
            union { unsigned u[4]; bf16x8 v; } pu;
            pu.u[0] = PKa[2 * ks];
            pu.u[1] = PKb[2 * ks];
            pu.u[2] = PKa[2 * ks + 1];
            pu.u[3] = PKb[2 * ks + 1];
            pa[ks] = pu.v;
        }

        // PV (V masked-zero in memory) + indicator-MFMA for l
        __builtin_amdgcn_s_setprio(1);
#pragma unroll
        for (int ks = 0; ks < 4; ks++) {
            Y0 = mfma32(pa[ks], vb0[ks], Y0);
            Y1 = mfma32(pa[ks], vb1[ks], Y1);
            Yl = mfma32(pa[ks], im[ks],  Yl);
        }
        __builtin_amdgcn_s_setprio(0);

        __syncthreads();   // drains K stage loads (next buffer) + all reads of cur
    }

    // ---- epilogue: normalize and store (Yl[reg] = row sum l for that q-row) ----
#pragma unroll
    for (int reg = 0; reg < 16; reg++) {
        float lv = (anyb != 0ull) ? (1.0f / Yl[reg]) : 0.f;
        int row = (reg & 3) + 8 * (reg >> 2) + 4 * hi;
        int n = q0 + row;
        size_t base = ((size_t)b * SEQ + n) * DMODEL + h * DHEAD;
        Zt[base + ql] = f2bf(Y0[reg] * lv);
        Zt[base + 32 + ql] = f2bf(Y1[reg] * lv);
    }
}

extern "C" void kernel_launch(void* const* d_in, const int* in_sizes, int n_in,
                              void* d_out, int out_size, void* d_ws, size_t ws_size,
                              hipStream_t stream) {
    const float* query = (const float*)d_in[0];
    const float* Wq = (const float*)d_in[1];
    const float* bq = (const float*)d_in[2];
    const float* Wk = (const float*)d_in[3];
    const float* bk = (const float*)d_in[4];
    const float* Wv = (const float*)d_in[5];
    const float* bv = (const float*)d_in[6];
    const float* Wo = (const float*)d_in[7];
    const float* bo = (const float*)d_in[8];
    const int* mask = (const int*)d_in[9];
    float* out = (float*)d_out;

    char* ws = (char*)d_ws;
    unsigned short* Wb  = (unsigned short*)(ws);                      // 8MB (Wq|Wk|Wv|Wo)
    unsigned short* Xt  = (unsigned short*)(ws + ((size_t)8  << 20)); // 8MB
    unsigned short* Qb  = (unsigned short*)(ws + ((size_t)16 << 20)); // 8MB
    unsigned short* Kbuf= (unsigned short*)(ws + ((size_t)24 << 20)); // 8MB (row layout)
    unsigned short* Vtb = (unsigned short*)(ws + ((size_t)32 << 20)); // 8MB (fragment layout)
    unsigned short* Zt  = (unsigned short*)(ws + ((size_t)40 << 20)); // 8MB
    unsigned long long* mwords = (unsigned long long*)(ws + ((size_t)48 << 20)); // 512B
    unsigned short* maskvb = (unsigned short*)(ws + ((size_t)48 << 20) + 65536); // 8KB

    const size_t WSZ = (size_t)DMODEL * DMODEL;

    cvt_w<<<dim3(DMODEL * DMODEL / 1024, 4), 256, 0, stream>>>(Wq, Wk, Wv, Wo, Wb);
    prep_mask<<<64, 64, 0, stream>>>(mask, mwords, maskvb);
    transpose_q<<<dim3(SEQ / 32, DMODEL / 32, BATCH), dim3(32, 8), 0, stream>>>(query, Xt);

    gemm_qkv<<<dim3(3 * DMODEL / 128, COLS / 128), 256, 0, stream>>>(
        Xt, Wb, bq, bk, bv, mask, Qb, Kbuf, Vtb);

    attn<<<512, 256, 0, stream>>>(Qb, Kbuf, Vtb, mwords, maskvb, Zt);

    gemm_out<<<dim3(COLS / 64, DMODEL / 128), 256, 0, stream>>>(
        Wb + 3 * WSZ, Zt, bo, out);
}